// Round 1
// baseline (645.716 us; speedup 1.0000x reference)
//
#include <hip/hip_runtime.h>
#include <cstdint>
#include <cstddef>

#define B_SZ   8
#define L_SEQ  4096
#define DM     1024
#define NS     64      // D_STATE
#define NP     192     // reduced projection rows (delta 64 + Bmean 64 + Cmean 64)
#define EPS_C  1e-4f

#define TT     32      // timesteps per K1 block
#define KC     32      // K-chunk (channels per stage)

// ---------------- K0: build reduced projection matrix W' (192 x 1024) ----------------
__global__ __launch_bounds__(256) void k0_prep(const float* __restrict__ Wi, float* __restrict__ Wp) {
    int idx = blockIdx.x * 256 + threadIdx.x;
    if (idx >= NP * DM) return;
    int n = idx >> 10;
    int c = idx & (DM - 1);
    float v;
    if (n < 64) {
        v = Wi[n * DM + c];
    } else if (n < 128) {
        int i = n - 64;
        v = 0.5f * (Wi[(64 + 2 * i) * DM + c] + Wi[(64 + 2 * i + 1) * DM + c]);
    } else {
        int i = n - 128;
        v = 0.5f * (Wi[(192 + 2 * i) * DM + c] + Wi[(192 + 2 * i + 1) * DM + c]);
    }
    Wp[idx] = v;
}

// ---------------- K1: fused conv1d + in_proj GEMM + elementwise -> Abar, Bbar, C ----------------
__global__ __launch_bounds__(256) void k1_convproj(
    const float* __restrict__ x, const float* __restrict__ conv_w,
    const float* __restrict__ conv_b, const float* __restrict__ in_proj_b,
    const float* __restrict__ A_log, const float* __restrict__ Wp,
    float* __restrict__ Abar, float* __restrict__ Bbar, float* __restrict__ Cst)
{
    __shared__ float  x_lds[(TT + 3) * KC];
    __shared__ float  xc_lds[TT * KC];
    __shared__ float  w_lds[KC * NP];
    __shared__ float4 cw4[KC];
    __shared__ float  cb_lds[KC];

    const int tid = threadIdx.x;
    const int tx  = tid & 63;
    const int ty  = tid >> 6;
    const int b   = blockIdx.x >> 7;             // 128 tiles per batch
    const int t0  = (blockIdx.x & 127) * TT;

    float acc[8][3];
#pragma unroll
    for (int t = 0; t < 8; ++t) { acc[t][0] = 0.f; acc[t][1] = 0.f; acc[t][2] = 0.f; }

    for (int k0 = 0; k0 < DM; k0 += KC) {
        // stage conv weights/bias for this channel chunk
        if (tid < KC) {
            cw4[tid]    = *(const float4*)&conv_w[(k0 + tid) * 4];
            cb_lds[tid] = conv_b[k0 + tid];
        }
        // stage x rows [t0-1 .. t0+TT+1] for channels [k0, k0+KC)
        for (int idx = tid; idx < (TT + 3) * KC; idx += 256) {
            int r = idx / KC, cc = idx - r * KC;
            int g = t0 + r - 1;
            float v = 0.f;
            if (g >= 0 && g < L_SEQ)
                v = x[((size_t)(b * L_SEQ + g)) * DM + (k0 + cc)];
            x_lds[idx] = v;
        }
        // stage W' chunk transposed: w_lds[kk][n]
        for (int idx = tid; idx < NP * (KC / 4); idx += 256) {
            int n = idx >> 3, kq = idx & 7;
            float4 v = *(const float4*)&Wp[(size_t)n * DM + k0 + kq * 4];
            w_lds[(kq * 4 + 0) * NP + n] = v.x;
            w_lds[(kq * 4 + 1) * NP + n] = v.y;
            w_lds[(kq * 4 + 2) * NP + n] = v.z;
            w_lds[(kq * 4 + 3) * NP + n] = v.w;
        }
        __syncthreads();
        // conv -> xc  (xc[t][c] = conv_b[c] + sum_k w[c][k]*x[t-1+k][c]; row L-1 is exact zero)
        for (int idx = tid; idx < TT * KC; idx += 256) {
            int t = idx / KC, cc = idx - t * KC;
            float v = 0.f;
            if (t0 + t != L_SEQ - 1) {
                float4 w4 = cw4[cc];
                v = cb_lds[cc];
                v = fmaf(w4.x, x_lds[(t + 0) * KC + cc], v);
                v = fmaf(w4.y, x_lds[(t + 1) * KC + cc], v);
                v = fmaf(w4.z, x_lds[(t + 2) * KC + cc], v);
                v = fmaf(w4.w, x_lds[(t + 3) * KC + cc], v);
            }
            xc_lds[idx] = v;
        }
        __syncthreads();
        // GEMM: acc[t][j] += xc[t][kk] * W'[n_j][kk]
        for (int kk4 = 0; kk4 < KC / 4; ++kk4) {
            float wr[4][3];
#pragma unroll
            for (int j = 0; j < 4; ++j) {
                int kk = kk4 * 4 + j;
                wr[j][0] = w_lds[kk * NP + tx];
                wr[j][1] = w_lds[kk * NP + tx + 64];
                wr[j][2] = w_lds[kk * NP + tx + 128];
            }
#pragma unroll
            for (int t = 0; t < 8; ++t) {
                float4 xv = *(const float4*)&xc_lds[(ty * 8 + t) * KC + kk4 * 4];
                acc[t][0] = fmaf(xv.x, wr[0][0], acc[t][0]);
                acc[t][1] = fmaf(xv.x, wr[0][1], acc[t][1]);
                acc[t][2] = fmaf(xv.x, wr[0][2], acc[t][2]);
                acc[t][0] = fmaf(xv.y, wr[1][0], acc[t][0]);
                acc[t][1] = fmaf(xv.y, wr[1][1], acc[t][1]);
                acc[t][2] = fmaf(xv.y, wr[1][2], acc[t][2]);
                acc[t][0] = fmaf(xv.z, wr[2][0], acc[t][0]);
                acc[t][1] = fmaf(xv.z, wr[2][1], acc[t][1]);
                acc[t][2] = fmaf(xv.z, wr[2][2], acc[t][2]);
                acc[t][0] = fmaf(xv.w, wr[3][0], acc[t][0]);
                acc[t][1] = fmaf(xv.w, wr[3][1], acc[t][1]);
                acc[t][2] = fmaf(xv.w, wr[3][2], acc[t][2]);
            }
        }
        __syncthreads();
    }

    // epilogue: per-(t,i) elementwise SSM parameterization, i = tx
    const int i = tx;
    const float A  = -expf(A_log[i]);
    const float bd = in_proj_b[i];
    const float bB = 0.5f * (in_proj_b[64 + 2 * i] + in_proj_b[64 + 2 * i + 1]);
    const float bC = 0.5f * (in_proj_b[192 + 2 * i] + in_proj_b[192 + 2 * i + 1]);
    const bool tiny = fabsf(A) < EPS_C;
#pragma unroll
    for (int t = 0; t < 8; ++t) {
        int gt = t0 + ty * 8 + t;
        float d  = acc[t][0] + bd;
        float Bm = acc[t][1] + bB;
        float Cm = acc[t][2] + bC;
        float delta = (d > 20.f) ? d : log1pf(expf(d));
        float dA = delta * A;
        float abar = expf(dA);
        float sc;
        if (tiny) sc = 1.f + dA * 0.5f + dA * dA * (1.f / 6.f);
        else      sc = (abar - 1.f) / A;
        float bbar = sc * Bm;
        size_t o = ((size_t)(b * L_SEQ + gt)) * NS + i;
        Abar[o] = abar;
        Bbar[o] = bbar;
        Cst[o]  = Cm;
    }
}

// ---------------- K2a: per-64-step-chunk (P = prod a, S = local scan end) ----------------
__global__ __launch_bounds__(256) void k2_scan1(const float* __restrict__ Abar, const float* __restrict__ Bbar,
                                                float* __restrict__ Psum, float* __restrict__ Ssum) {
    int b  = blockIdx.x >> 4;      // 16 blocks per batch
    int cb = blockIdx.x & 15;
    int w  = threadIdx.x >> 6;
    int i  = threadIdx.x & 63;
    int c  = cb * 4 + w;           // chunk index 0..63
    float P = 1.f, S = 0.f;
    size_t base = ((size_t)b * L_SEQ + (size_t)c * 64) * NS + i;
    for (int t = 0; t < 64; ++t) {
        float a  = Abar[base + (size_t)t * NS];
        float bb = Bbar[base + (size_t)t * NS];
        S = fmaf(a, S, bb);
        P *= a;
    }
    size_t o = ((size_t)(b * 64 + c)) * NS + i;
    Psum[o] = P;
    Ssum[o] = S;
}

// ---------------- K2b: serial carry combine across 64 chunks ----------------
__global__ __launch_bounds__(64) void k2_scan2(const float* __restrict__ Psum, const float* __restrict__ Ssum,
                                               float* __restrict__ Carry) {
    int b = blockIdx.x;
    int i = threadIdx.x;
    float h = 0.f;
    for (int c = 0; c < 64; ++c) {
        size_t o = ((size_t)(b * 64 + c)) * NS + i;
        Carry[o] = h;
        h = fmaf(Psum[o], h, Ssum[o]);
    }
}

// ---------------- K2c: re-scan with carry, y = C * h ----------------
__global__ __launch_bounds__(256) void k2_scan3(const float* __restrict__ Abar, const float* __restrict__ Bbar,
                                                const float* __restrict__ Cst, const float* __restrict__ Carry,
                                                float* __restrict__ Ys) {
    int b  = blockIdx.x >> 4;
    int cb = blockIdx.x & 15;
    int w  = threadIdx.x >> 6;
    int i  = threadIdx.x & 63;
    int c  = cb * 4 + w;
    float h = Carry[((size_t)(b * 64 + c)) * NS + i];
    size_t base = ((size_t)b * L_SEQ + (size_t)c * 64) * NS + i;
#pragma unroll 4
    for (int t = 0; t < 64; ++t) {
        size_t o = base + (size_t)t * NS;
        float a  = Abar[o];
        float bb = Bbar[o];
        h = fmaf(a, h, bb);
        Ys[o] = Cst[o] * h;
    }
}

// ---------------- K4: out_proj GEMM (32768x64)·(64x1024) + bias ----------------
__global__ __launch_bounds__(256) void k4_outproj(const float* __restrict__ Ys, const float* __restrict__ Wo,
                                                  const float* __restrict__ bo, float* __restrict__ out) {
    __shared__ float y_lds[16][64];
    const int tid = threadIdx.x;
    const size_t r0 = (size_t)blockIdx.x * 16;
    {
        int t = tid >> 6, i = tid & 63;
#pragma unroll
        for (int p = 0; p < 4; ++p)
            y_lds[t + p * 4][i] = Ys[(r0 + t + p * 4) * NS + i];
    }
    __syncthreads();
    float acc[16][4];
#pragma unroll
    for (int t = 0; t < 16; ++t) {
#pragma unroll
        for (int j = 0; j < 4; ++j) acc[t][j] = 0.f;
    }
    for (int i0 = 0; i0 < 64; i0 += 4) {
        float4 w4[4];
#pragma unroll
        for (int j = 0; j < 4; ++j)
            w4[j] = *(const float4*)&Wo[(size_t)(tid + 256 * j) * NS + i0];
#pragma unroll
        for (int t = 0; t < 16; ++t) {
            float4 y4 = *(const float4*)&y_lds[t][i0];
#pragma unroll
            for (int j = 0; j < 4; ++j) {
                acc[t][j] = fmaf(y4.x, w4[j].x, acc[t][j]);
                acc[t][j] = fmaf(y4.y, w4[j].y, acc[t][j]);
                acc[t][j] = fmaf(y4.z, w4[j].z, acc[t][j]);
                acc[t][j] = fmaf(y4.w, w4[j].w, acc[t][j]);
            }
        }
    }
#pragma unroll
    for (int j = 0; j < 4; ++j) {
        float bj = bo[tid + 256 * j];
#pragma unroll
        for (int t = 0; t < 16; ++t)
            out[(r0 + t) * DM + tid + 256 * j] = acc[t][j] + bj;
    }
}

extern "C" void kernel_launch(void* const* d_in, const int* in_sizes, int n_in,
                              void* d_out, int out_size, void* d_ws, size_t ws_size,
                              hipStream_t stream) {
    const float* x          = (const float*)d_in[0];
    const float* conv_w     = (const float*)d_in[1];
    const float* conv_b     = (const float*)d_in[2];
    const float* in_proj_w  = (const float*)d_in[3];
    const float* in_proj_b  = (const float*)d_in[4];
    const float* A_log      = (const float*)d_in[5];
    const float* out_proj_w = (const float*)d_in[6];
    const float* out_proj_b = (const float*)d_in[7];
    float* out = (float*)d_out;

    float* ws    = (float*)d_ws;
    float* Wp    = ws;                 // 192*1024        = 196608
    float* Abar  = Wp   + 196608;      // 8*4096*64       = 2097152
    float* Bbar  = Abar + 2097152;
    float* Cst   = Bbar + 2097152;
    float* Ys    = Cst  + 2097152;
    float* Psum  = Ys   + 2097152;     // 8*64*64         = 32768
    float* Ssum  = Psum + 32768;
    float* Carry = Ssum + 32768;

    hipLaunchKernelGGL(k0_prep,     dim3(768),  dim3(256), 0, stream, in_proj_w, Wp);
    hipLaunchKernelGGL(k1_convproj, dim3(1024), dim3(256), 0, stream,
                       x, conv_w, conv_b, in_proj_b, A_log, Wp, Abar, Bbar, Cst);
    hipLaunchKernelGGL(k2_scan1,    dim3(128),  dim3(256), 0, stream, Abar, Bbar, Psum, Ssum);
    hipLaunchKernelGGL(k2_scan2,    dim3(8),    dim3(64),  0, stream, Psum, Ssum, Carry);
    hipLaunchKernelGGL(k2_scan3,    dim3(128),  dim3(256), 0, stream, Abar, Bbar, Cst, Carry, Ys);
    hipLaunchKernelGGL(k4_outproj,  dim3(2048), dim3(256), 0, stream, Ys, out_proj_w, out_proj_b, out);
}

// Round 2
// 351.576 us; speedup vs baseline: 1.8366x; 1.8366x over previous
//
#include <hip/hip_runtime.h>
#include <cstdint>
#include <cstddef>

#define B_SZ   8
#define L_SEQ  4096
#define DM     1024
#define NS     64      // D_STATE
#define NP     192     // reduced projection rows (delta 64 + Bmean 64 + Cmean 64)
#define EPS_C  1e-4f

// ---- K1 geometry: lane = timestep, weights in SGPR ----
#define TT1    64      // timesteps per block
#define KC1    64      // channels per chunk
#define TH1    512     // threads (8 waves)
#define NPW    24      // output rows per wave (8*24 = 192)
#define XROWS  67      // TT1 + 3 halo rows
#define XPITCH 66      // floats per x row: 2-way bank alias (free), 8B-aligned
#define PPITCH 65      // epilogue transpose pitch: 2-way alias

// ---------------- K0: reduced projection matrix, k-major: Wt[k][n], 1024 x 192 ----------------
__global__ __launch_bounds__(256) void k0_prep(const float* __restrict__ Wi, float* __restrict__ Wt) {
    int idx = blockIdx.x * 256 + threadIdx.x;
    if (idx >= NP * DM) return;
    int k = idx / NP;          // 0..1023
    int n = idx - k * NP;      // 0..191
    float v;
    if (n < 64) {
        v = Wi[n * DM + k];
    } else if (n < 128) {
        int i = n - 64;
        v = 0.5f * (Wi[(64 + 2 * i) * DM + k] + Wi[(64 + 2 * i + 1) * DM + k]);
    } else {
        int i = n - 128;
        v = 0.5f * (Wi[(192 + 2 * i) * DM + k] + Wi[(192 + 2 * i + 1) * DM + k]);
    }
    Wt[idx] = v;
}

// ---------------- K1: fused conv1d + in_proj GEMM + elementwise -> Abar, Bbar, C ----------------
__global__ __launch_bounds__(TH1) void k1_convproj(
    const float* __restrict__ x, const float* __restrict__ conv_w,
    const float* __restrict__ conv_b, const float* __restrict__ in_proj_b,
    const float* __restrict__ A_log, const float* __restrict__ Wt,
    float* __restrict__ Abar, float* __restrict__ Bbar, float* __restrict__ Cst)
{
    __shared__ float smem[NP * PPITCH];        // 12480 floats = 49.9 KB (epilogue view)
    float* x_l  = smem;                        // [67][66]  (chunk x staging)
    float* xc_l = smem + 4424;                 // [64][64]  ([c][t] conv output)

    const int tid  = threadIdx.x;
    const int lane = tid & 63;
    const int wv   = __builtin_amdgcn_readfirstlane(tid >> 6);
    const int n0   = wv * NPW;
    const int b    = blockIdx.x >> 6;          // 64 tiles per batch
    const int t0   = (blockIdx.x & 63) * TT1;

    float acc[NPW];
#pragma unroll
    for (int n = 0; n < NPW; ++n) acc[n] = 0.f;

    // prologue: load chunk 0's x into regs, write to LDS
    float4 st[3];
#pragma unroll
    for (int p = 0; p < 3; ++p) {
        int idx = tid + p * TH1;
        float4 v = {0.f, 0.f, 0.f, 0.f};
        if (idx < XROWS * 16) {
            int row = idx >> 4, c4 = idx & 15;
            int g = t0 - 1 + row;
            if (g >= 0 && g < L_SEQ)
                v = *(const float4*)&x[((size_t)(b * L_SEQ + g)) * DM + c4 * 4];
        }
        st[p] = v;
    }
#pragma unroll
    for (int p = 0; p < 3; ++p) {
        int idx = tid + p * TH1;
        if (idx < XROWS * 16) {
            int row = idx >> 4, c4 = idx & 15;
            float* dst = &x_l[row * XPITCH + c4 * 4];
            *(float2*)dst       = make_float2(st[p].x, st[p].y);
            *(float2*)(dst + 2) = make_float2(st[p].z, st[p].w);
        }
    }

    for (int k0 = 0; k0 < DM; k0 += KC1) {
        __syncthreads();                       // x_l(k0) visible to all
        // ---- conv: per wave 8 channels, lane = t; 2-way LDS reads ----
        {
            const int t = lane;
            const bool zero = (t0 + t == L_SEQ - 1);   // reference pads last conv row with 0
#pragma unroll
            for (int j = 0; j < 8; ++j) {
                int c = wv * 8 + j;
                float v = 0.f;
                if (!zero) {
                    const float4 w4 = *(const float4*)&conv_w[(k0 + c) * 4];   // wave-uniform -> s_load
                    v = conv_b[k0 + c];
                    v = fmaf(w4.x, x_l[(t + 0) * XPITCH + c], v);
                    v = fmaf(w4.y, x_l[(t + 1) * XPITCH + c], v);
                    v = fmaf(w4.z, x_l[(t + 2) * XPITCH + c], v);
                    v = fmaf(w4.w, x_l[(t + 3) * XPITCH + c], v);
                }
                xc_l[c * TT1 + t] = v;         // lanes consecutive -> conflict-free
            }
        }
        __syncthreads();                       // xc ready, x_l dead
        // ---- issue next chunk's x loads (hide HBM latency under GEMM) ----
        const bool more = (k0 + KC1 < DM);
        if (more) {
#pragma unroll
            for (int p = 0; p < 3; ++p) {
                int idx = tid + p * TH1;
                float4 v = {0.f, 0.f, 0.f, 0.f};
                if (idx < XROWS * 16) {
                    int row = idx >> 4, c4 = idx & 15;
                    int g = t0 - 1 + row;
                    if (g >= 0 && g < L_SEQ)
                        v = *(const float4*)&x[((size_t)(b * L_SEQ + g)) * DM + (k0 + KC1) + c4 * 4];
                }
                st[p] = v;
            }
        }
        // ---- GEMM: weights wave-uniform (SGPR), x per-lane (1 ds_read_b32 / 24 FMA) ----
        {
            const float* __restrict__ wr = Wt + (size_t)k0 * NP + n0;
#pragma unroll 2
            for (int kk = 0; kk < KC1; ++kk) {
                float xv = xc_l[kk * TT1 + lane];
                const float* __restrict__ w = wr + kk * NP;
#pragma unroll
                for (int n = 0; n < NPW; ++n)
                    acc[n] = fmaf(w[n], xv, acc[n]);
            }
        }
        // ---- write next chunk's x to LDS (safe: all waves past conv(k0)) ----
        if (more) {
#pragma unroll
            for (int p = 0; p < 3; ++p) {
                int idx = tid + p * TH1;
                if (idx < XROWS * 16) {
                    int row = idx >> 4, c4 = idx & 15;
                    float* dst = &x_l[row * XPITCH + c4 * 4];
                    *(float2*)dst       = make_float2(st[p].x, st[p].y);
                    *(float2*)(dst + 2) = make_float2(st[p].z, st[p].w);
                }
            }
        }
        __syncthreads();                       // xc_l reads done before next conv overwrites
    }

    // ---- epilogue: cross-wave transpose through LDS, then SSM elementwise ----
    float* p_l = smem;
#pragma unroll
    for (int n = 0; n < NPW; ++n)
        p_l[(n0 + n) * PPITCH + lane] = acc[n];   // lanes consecutive -> conflict-free
    __syncthreads();

    const int i  = lane;
    const int tr = tid >> 6;
    const float A  = -expf(A_log[i]);
    const float bd = in_proj_b[i];
    const float bB = 0.5f * (in_proj_b[64 + 2 * i] + in_proj_b[64 + 2 * i + 1]);
    const float bC = 0.5f * (in_proj_b[192 + 2 * i] + in_proj_b[192 + 2 * i + 1]);
    const bool tiny = fabsf(A) < EPS_C;
#pragma unroll
    for (int r = 0; r < 8; ++r) {
        int t = tr * 8 + r;
        float d  = p_l[i * PPITCH + t] + bd;             // 2-way alias reads
        float Bm = p_l[(64 + i) * PPITCH + t] + bB;
        float Cm = p_l[(128 + i) * PPITCH + t] + bC;
        float delta = (d > 20.f) ? d : log1pf(expf(d));
        float dA = delta * A;
        float abar = expf(dA);
        float sc;
        if (tiny) sc = 1.f + dA * 0.5f + dA * dA * (1.f / 6.f);
        else      sc = (abar - 1.f) / A;
        float bbar = sc * Bm;
        size_t o = ((size_t)(b * L_SEQ + t0 + t)) * NS + i;
        Abar[o] = abar;
        Bbar[o] = bbar;
        Cst[o]  = Cm;
    }
}

// ---------------- K2a: per-64-step-chunk (P = prod a, S = local scan end) ----------------
__global__ __launch_bounds__(256) void k2_scan1(const float* __restrict__ Abar, const float* __restrict__ Bbar,
                                                float* __restrict__ Psum, float* __restrict__ Ssum) {
    int b  = blockIdx.x >> 4;      // 16 blocks per batch
    int cb = blockIdx.x & 15;
    int w  = threadIdx.x >> 6;
    int i  = threadIdx.x & 63;
    int c  = cb * 4 + w;           // chunk index 0..63
    float P = 1.f, S = 0.f;
    size_t base = ((size_t)b * L_SEQ + (size_t)c * 64) * NS + i;
    for (int t = 0; t < 64; ++t) {
        float a  = Abar[base + (size_t)t * NS];
        float bb = Bbar[base + (size_t)t * NS];
        S = fmaf(a, S, bb);
        P *= a;
    }
    size_t o = ((size_t)(b * 64 + c)) * NS + i;
    Psum[o] = P;
    Ssum[o] = S;
}

// ---------------- K2b: serial carry combine across 64 chunks ----------------
__global__ __launch_bounds__(64) void k2_scan2(const float* __restrict__ Psum, const float* __restrict__ Ssum,
                                               float* __restrict__ Carry) {
    int b = blockIdx.x;
    int i = threadIdx.x;
    float h = 0.f;
    for (int c = 0; c < 64; ++c) {
        size_t o = ((size_t)(b * 64 + c)) * NS + i;
        Carry[o] = h;
        h = fmaf(Psum[o], h, Ssum[o]);
    }
}

// ---------------- K2c: re-scan with carry, y = C * h ----------------
__global__ __launch_bounds__(256) void k2_scan3(const float* __restrict__ Abar, const float* __restrict__ Bbar,
                                                const float* __restrict__ Cst, const float* __restrict__ Carry,
                                                float* __restrict__ Ys) {
    int b  = blockIdx.x >> 4;
    int cb = blockIdx.x & 15;
    int w  = threadIdx.x >> 6;
    int i  = threadIdx.x & 63;
    int c  = cb * 4 + w;
    float h = Carry[((size_t)(b * 64 + c)) * NS + i];
    size_t base = ((size_t)b * L_SEQ + (size_t)c * 64) * NS + i;
#pragma unroll 4
    for (int t = 0; t < 64; ++t) {
        size_t o = base + (size_t)t * NS;
        float a  = Abar[o];
        float bb = Bbar[o];
        h = fmaf(a, h, bb);
        Ys[o] = Cst[o] * h;
    }
}

// ---------------- K4: out_proj GEMM (32768x64)·(64x1024) + bias ----------------
__global__ __launch_bounds__(256) void k4_outproj(const float* __restrict__ Ys, const float* __restrict__ Wo,
                                                  const float* __restrict__ bo, float* __restrict__ out) {
    __shared__ float y_lds[16][64];
    const int tid = threadIdx.x;
    const size_t r0 = (size_t)blockIdx.x * 16;
    {
        int t = tid >> 6, i = tid & 63;
#pragma unroll
        for (int p = 0; p < 4; ++p)
            y_lds[t + p * 4][i] = Ys[(r0 + t + p * 4) * NS + i];
    }
    __syncthreads();
    float acc[16][4];
#pragma unroll
    for (int t = 0; t < 16; ++t) {
#pragma unroll
        for (int j = 0; j < 4; ++j) acc[t][j] = 0.f;
    }
    for (int i0 = 0; i0 < 64; i0 += 4) {
        float4 w4[4];
#pragma unroll
        for (int j = 0; j < 4; ++j)
            w4[j] = *(const float4*)&Wo[(size_t)(tid + 256 * j) * NS + i0];
#pragma unroll
        for (int t = 0; t < 16; ++t) {
            float4 y4 = *(const float4*)&y_lds[t][i0];
#pragma unroll
            for (int j = 0; j < 4; ++j) {
                acc[t][j] = fmaf(y4.x, w4[j].x, acc[t][j]);
                acc[t][j] = fmaf(y4.y, w4[j].y, acc[t][j]);
                acc[t][j] = fmaf(y4.z, w4[j].z, acc[t][j]);
                acc[t][j] = fmaf(y4.w, w4[j].w, acc[t][j]);
            }
        }
    }
#pragma unroll
    for (int j = 0; j < 4; ++j) {
        float bj = bo[tid + 256 * j];
#pragma unroll
        for (int t = 0; t < 16; ++t)
            out[(r0 + t) * DM + tid + 256 * j] = acc[t][j] + bj;
    }
}

extern "C" void kernel_launch(void* const* d_in, const int* in_sizes, int n_in,
                              void* d_out, int out_size, void* d_ws, size_t ws_size,
                              hipStream_t stream) {
    const float* x          = (const float*)d_in[0];
    const float* conv_w     = (const float*)d_in[1];
    const float* conv_b     = (const float*)d_in[2];
    const float* in_proj_w  = (const float*)d_in[3];
    const float* in_proj_b  = (const float*)d_in[4];
    const float* A_log      = (const float*)d_in[5];
    const float* out_proj_w = (const float*)d_in[6];
    const float* out_proj_b = (const float*)d_in[7];
    float* out = (float*)d_out;

    float* ws    = (float*)d_ws;
    float* Wt    = ws;                 // 1024*192        = 196608 (k-major)
    float* Abar  = Wt   + 196608;      // 8*4096*64       = 2097152
    float* Bbar  = Abar + 2097152;
    float* Cst   = Bbar + 2097152;
    float* Ys    = Cst  + 2097152;
    float* Psum  = Ys   + 2097152;     // 8*64*64         = 32768
    float* Ssum  = Psum + 32768;
    float* Carry = Ssum + 32768;

    hipLaunchKernelGGL(k0_prep,     dim3(768),  dim3(256), 0, stream, in_proj_w, Wt);
    hipLaunchKernelGGL(k1_convproj, dim3(512),  dim3(TH1), 0, stream,
                       x, conv_w, conv_b, in_proj_b, A_log, Wt, Abar, Bbar, Cst);
    hipLaunchKernelGGL(k2_scan1,    dim3(128),  dim3(256), 0, stream, Abar, Bbar, Psum, Ssum);
    hipLaunchKernelGGL(k2_scan2,    dim3(8),    dim3(64),  0, stream, Psum, Ssum, Carry);
    hipLaunchKernelGGL(k2_scan3,    dim3(128),  dim3(256), 0, stream, Abar, Bbar, Cst, Carry, Ys);
    hipLaunchKernelGGL(k4_outproj,  dim3(2048), dim3(256), 0, stream, Ys, out_proj_w, out_proj_b, out);
}

// Round 3
// 215.101 us; speedup vs baseline: 3.0019x; 1.6345x over previous
//
#include <hip/hip_runtime.h>
#include <cstdint>
#include <cstddef>

typedef __bf16 bf16;
typedef __attribute__((ext_vector_type(8))) __bf16 bf16x8;
typedef __attribute__((ext_vector_type(4))) float f32x4;

#define EPS_C 1e-4f

// ================= K0: weights prep =================
// Whg/Wlg: reduced in_proj (192 x 1024), n-major k-contig, split hi/lo bf16.
// Wob: out_proj_w cast to bf16, layout [dm=1024][i=64] (= B[k=i][n=dm] k-contig).
__global__ __launch_bounds__(256) void k0_prep(const float* __restrict__ Wi,
    const float* __restrict__ Wo, bf16* __restrict__ Whg, bf16* __restrict__ Wlg,
    bf16* __restrict__ Wob)
{
    int idx = blockIdx.x * 256 + threadIdx.x;
    if (idx < 192 * 1024) {
        int n = idx >> 10, k = idx & 1023;
        float w;
        if (n < 64) {
            w = Wi[n * 1024 + k];
        } else if (n < 128) {
            int i = n - 64;
            w = 0.5f * (Wi[(64 + 2 * i) * 1024 + k] + Wi[(65 + 2 * i) * 1024 + k]);
        } else {
            int i = n - 128;
            w = 0.5f * (Wi[(192 + 2 * i) * 1024 + k] + Wi[(193 + 2 * i) * 1024 + k]);
        }
        bf16 h = (bf16)w;
        Whg[idx] = h;
        Wlg[idx] = (bf16)(w - (float)h);
    } else {
        int j = idx - 192 * 1024;
        if (j < 65536) Wob[j] = (bf16)Wo[j];
    }
}

// ================= K1: conv + split-bf16 MFMA in_proj + SSM elementwise + scan1 =================
// 256 threads (4 waves). Block tile: 64 t x 192 n, BK=32, 32 chunks.
// Wave tile 64t x 48n: acc[4][3] frags; 3-pass split-bf16 -> fp32-accurate.
__global__ __launch_bounds__(256) void k1_convproj(
    const float* __restrict__ x, const float* __restrict__ conv_w,
    const float* __restrict__ conv_b, const float* __restrict__ in_proj_b,
    const float* __restrict__ A_log,
    const bf16* __restrict__ Whg, const bf16* __restrict__ Wlg,
    float* __restrict__ Abar, float* __restrict__ Bbar, float* __restrict__ Cst,
    float* __restrict__ Psum, float* __restrict__ Ssum)
{
    __shared__ char smem[53248];
    char*  xh_l = smem;                      // [64 t][32 k] bf16, swizzled 64B rows
    char*  xl_l = smem + 4096;
    char*  wh_l = smem + 8192;               // [192 n][32 k] bf16, swizzled
    char*  wl_l = smem + 20480;
    float* cwl  = (float*)(smem + 32768);    // conv_w copy [1024][4]
    float* cbl  = (float*)(smem + 49152);    // conv_b copy [1024]
    float* res  = (float*)smem;              // epilogue [64 t][196]
    float* part = (float*)(smem + 50176);    // [2][4][64]

    const int tid  = threadIdx.x;
    const int lane = tid & 63;
    const int wv   = tid >> 6;
    const int b    = blockIdx.x >> 6;
    const int t0   = (blockIdx.x & 63) * 64;

    // stage conv tables (dead by epilogue; res overlays them)
    for (int p = tid; p < 1024; p += 256)
        ((f32x4*)cwl)[p] = ((const f32x4*)conv_w)[p];
    if (tid < 256) ((f32x4*)cbl)[tid] = ((const f32x4*)conv_b)[tid];

    // conv assignment: thread -> (t = tid>>2, channel slot cs = tid&3 -> 8 channels)
    const int ct = tid >> 2;
    const int cs = tid & 3;
    const int gt = t0 + ct;

    // W staging assignment: 3 pieces of 16B per thread per buffer
    int wn[3], wslot[3];
#pragma unroll
    for (int p = 0; p < 3; ++p) { int idx = tid + 256 * p; wn[p] = idx >> 2; wslot[p] = idx & 3; }

    f32x4 xr[8];               // 4 taps x 8 channels
    uint4 wrh[3], wrl[3];

    auto fetch_x = [&](int k0) {
#pragma unroll
        for (int dt = 0; dt < 4; ++dt) {
            int g = gt - 1 + dt;
            const float* p = x + ((size_t)b * 4096 + g) * 1024 + k0 + cs * 8;
            bool ok = (g >= 0) && (g < 4096);
            f32x4 z = {0.f, 0.f, 0.f, 0.f};
            xr[dt * 2]     = ok ? *(const f32x4*)p       : z;
            xr[dt * 2 + 1] = ok ? *(const f32x4*)(p + 4) : z;
        }
    };
    auto fetch_w = [&](int k0) {
#pragma unroll
        for (int p = 0; p < 3; ++p) {
            const bf16* ph = Whg + (size_t)wn[p] * 1024 + k0 + wslot[p] * 8;
            const bf16* pl = Wlg + (size_t)wn[p] * 1024 + k0 + wslot[p] * 8;
            wrh[p] = *(const uint4*)ph;
            wrl[p] = *(const uint4*)pl;
        }
    };

    f32x4 acc[4][3] = {};

    fetch_x(0);
    fetch_w(0);
    __syncthreads();                         // conv tables ready

    const int fr = lane & 15, fs = lane >> 4;

#pragma unroll 1
    for (int c = 0; c < 32; ++c) {
        const int k0 = c * 32;
        // ---- conv from prefetched regs (VALU) ----
        bf16x8 hi, lo;
#pragma unroll
        for (int j = 0; j < 8; ++j) { hi[j] = (bf16)0.f; lo[j] = (bf16)0.f; }
        if (gt != 4095) {                    // reference zero-pads last conv row
#pragma unroll
            for (int j = 0; j < 8; ++j) {
                int ch = k0 + cs * 8 + j;
                f32x4 cw = *(const f32x4*)&cwl[ch * 4];
                float v = cbl[ch];
                v = fmaf(cw.x, xr[0 + (j >> 2)][j & 3], v);
                v = fmaf(cw.y, xr[2 + (j >> 2)][j & 3], v);
                v = fmaf(cw.z, xr[4 + (j >> 2)][j & 3], v);
                v = fmaf(cw.w, xr[6 + (j >> 2)][j & 3], v);
                bf16 h = (bf16)v;
                hi[j] = h;
                lo[j] = (bf16)(v - (float)h);
            }
        }
        __syncthreads();                     // prev chunk's frag reads complete
        // ---- write x tiles (swizzled slot ^= (row>>1)&3) ----
        {
            int off = ct * 64 + (((cs ^ ((ct >> 1) & 3)) & 3) << 4);
            *(bf16x8*)(xh_l + off) = hi;
            *(bf16x8*)(xl_l + off) = lo;
        }
        // ---- write W tiles from prefetched regs ----
#pragma unroll
        for (int p = 0; p < 3; ++p) {
            int off = wn[p] * 64 + (((wslot[p] ^ ((wn[p] >> 1) & 3)) & 3) << 4);
            *(uint4*)(wh_l + off) = wrh[p];
            *(uint4*)(wl_l + off) = wrl[p];
        }
        __syncthreads();                     // tiles ready
        // ---- prefetch next chunk (latency hides under MFMA) ----
        if (c + 1 < 32) { fetch_x(k0 + 32); fetch_w(k0 + 32); }
        // ---- fragments + 3-pass MFMA ----
        bf16x8 ah[4], al[4];
#pragma unroll
        for (int mi = 0; mi < 4; ++mi) {
            int row = mi * 16 + fr;
            int off = row * 64 + (((fs ^ ((row >> 1) & 3)) & 3) << 4);
            ah[mi] = *(const bf16x8*)(xh_l + off);
            al[mi] = *(const bf16x8*)(xl_l + off);
        }
#pragma unroll
        for (int ni = 0; ni < 3; ++ni) {
            int row = wv * 48 + ni * 16 + fr;
            int off = row * 64 + (((fs ^ ((row >> 1) & 3)) & 3) << 4);
            bf16x8 bh = *(const bf16x8*)(wh_l + off);
            bf16x8 bl = *(const bf16x8*)(wl_l + off);
#pragma unroll
            for (int mi = 0; mi < 4; ++mi) {
                acc[mi][ni] = __builtin_amdgcn_mfma_f32_16x16x32_bf16(ah[mi], bh, acc[mi][ni], 0, 0, 0);
                acc[mi][ni] = __builtin_amdgcn_mfma_f32_16x16x32_bf16(al[mi], bh, acc[mi][ni], 0, 0, 0);
                acc[mi][ni] = __builtin_amdgcn_mfma_f32_16x16x32_bf16(ah[mi], bl, acc[mi][ni], 0, 0, 0);
            }
        }
    }

    // ---- epilogue: acc -> res[t][n], then SSM elementwise + fused scan1 ----
    __syncthreads();
#pragma unroll
    for (int mi = 0; mi < 4; ++mi)
#pragma unroll
        for (int ni = 0; ni < 3; ++ni) {
            int col = wv * 48 + ni * 16 + fr;
#pragma unroll
            for (int r = 0; r < 4; ++r) {
                int t = mi * 16 + fs * 4 + r;
                res[t * 196 + col] = acc[mi][ni][r];
            }
        }
    __syncthreads();

    const int i  = tid & 63;
    const int tg = tid >> 6;
    const float A  = -expf(A_log[i]);
    const float bd = in_proj_b[i];
    const float bB = 0.5f * (in_proj_b[64 + 2 * i] + in_proj_b[65 + 2 * i]);
    const float bC = 0.5f * (in_proj_b[192 + 2 * i] + in_proj_b[193 + 2 * i]);
    const bool tiny = fabsf(A) < EPS_C;
    float P = 1.f, S = 0.f;
#pragma unroll
    for (int r = 0; r < 16; ++r) {
        int t = tg * 16 + r;
        float d  = res[t * 196 + i]        + bd;
        float Bm = res[t * 196 + 64 + i]   + bB;
        float Cm = res[t * 196 + 128 + i]  + bC;
        float delta = (d > 20.f) ? d : log1pf(expf(d));
        float dA = delta * A;
        float abar = expf(dA);
        float sc = tiny ? (1.f + dA * 0.5f + dA * dA * (1.f / 6.f)) : ((abar - 1.f) / A);
        float bbar = sc * Bm;
        size_t o = ((size_t)(b * 4096) + t0 + t) * 64 + i;
        Abar[o] = abar; Bbar[o] = bbar; Cst[o] = Cm;
        S = fmaf(abar, S, bbar);
        P *= abar;
    }
    part[tg * 64 + i] = P;
    part[256 + tg * 64 + i] = S;
    __syncthreads();
    if (tid < 64) {
        float Pt = 1.f, St = 0.f;
#pragma unroll
        for (int g = 0; g < 4; ++g) {
            float Pg = part[g * 64 + tid], Sg = part[256 + g * 64 + tid];
            St = fmaf(Pg, St, Sg);
            Pt *= Pg;
        }
        size_t o = ((size_t)(b * 64) + (blockIdx.x & 63)) * 64 + tid;
        Psum[o] = Pt; Ssum[o] = St;
    }
}

// ================= K2: serial carry combine (batched loads, short FMA chain) =================
__global__ __launch_bounds__(64) void k2_scan2(const float* __restrict__ Psum,
    const float* __restrict__ Ssum, float* __restrict__ Carry)
{
    int b = blockIdx.x, i = threadIdx.x;
    float Pv[64], Sv[64];
#pragma unroll
    for (int c = 0; c < 64; ++c) {
        size_t o = ((size_t)(b * 64) + c) * 64 + i;
        Pv[c] = Psum[o]; Sv[c] = Ssum[o];
    }
    float h = 0.f;
#pragma unroll
    for (int c = 0; c < 64; ++c) {
        size_t o = ((size_t)(b * 64) + c) * 64 + i;
        Carry[o] = h;
        h = fmaf(Pv[c], h, Sv[c]);
    }
}

// ================= K3: re-scan + fused out_proj MFMA (bf16 1-pass, K=64) =================
// 512 threads (8 waves). Block = (b, 64-t chunk). Wave: 64t x 128n of output.
__global__ __launch_bounds__(512) void k3_scan_out(
    const float* __restrict__ Abar, const float* __restrict__ Bbar,
    const float* __restrict__ Cst, const float* __restrict__ Carry,
    const bf16* __restrict__ Wob, const float* __restrict__ bo,
    float* __restrict__ out)
{
    __shared__ char sm3[12288];
    char*  ysm  = sm3;                       // [64 t][64 i] bf16, swizzled 128B rows
    float* part = (float*)(sm3 + 8192);      // [2][8][64]

    const int tid  = threadIdx.x;
    const int lane = tid & 63;
    const int wv   = tid >> 6;               // 0..7
    const int b    = blockIdx.x >> 6;
    const int ch   = blockIdx.x & 63;
    const int t0   = ch * 64;

    // ---- phase 1: chunk-local scan, 8 groups of 8 t ----
    const int i  = lane;
    const int tg = wv;
    float av[8], bv[8], cv[8];
    size_t base = ((size_t)(b * 4096) + t0 + tg * 8) * 64 + i;
#pragma unroll
    for (int r = 0; r < 8; ++r) {
        av[r] = Abar[base + (size_t)r * 64];
        bv[r] = Bbar[base + (size_t)r * 64];
        cv[r] = Cst [base + (size_t)r * 64];
    }
    float P = 1.f, S = 0.f;
#pragma unroll
    for (int r = 0; r < 8; ++r) { S = fmaf(av[r], S, bv[r]); P *= av[r]; }
    part[tg * 64 + i] = P;
    part[512 + tg * 64 + i] = S;
    __syncthreads();
    float h = Carry[((size_t)(b * 64) + ch) * 64 + i];
#pragma unroll
    for (int g = 0; g < 7; ++g)
        if (g < tg) h = fmaf(part[g * 64 + i], h, part[512 + g * 64 + i]);
#pragma unroll
    for (int r = 0; r < 8; ++r) {
        h = fmaf(av[r], h, bv[r]);
        float y = cv[r] * h;
        int t = tg * 8 + r;
        int off = t * 128 + ((((i >> 3) ^ (t & 7)) & 7) << 4) + (i & 7) * 2;
        *(bf16*)(ysm + off) = (bf16)y;
    }
    __syncthreads();

    // ---- phase 2: out = y(64x64) @ Wob^T(64x1024) + bias ----
    const int fr = lane & 15, fs = lane >> 4;
    bf16x8 afr[4][2];
#pragma unroll
    for (int mi = 0; mi < 4; ++mi)
#pragma unroll
        for (int ks = 0; ks < 2; ++ks) {
            int row = mi * 16 + fr;
            int slot = ks * 4 + fs;
            int off = row * 128 + (((slot ^ (row & 7)) & 7) << 4);
            afr[mi][ks] = *(const bf16x8*)(ysm + off);
        }
    const int n0 = wv * 128;
#pragma unroll
    for (int ni = 0; ni < 8; ++ni) {
        int col = n0 + ni * 16 + fr;
        bf16x8 b0 = *(const bf16x8*)(Wob + (size_t)col * 64 + fs * 8);
        bf16x8 b1 = *(const bf16x8*)(Wob + (size_t)col * 64 + 32 + fs * 8);
        float bias = bo[col];
#pragma unroll
        for (int mi = 0; mi < 4; ++mi) {
            f32x4 a = {};
            a = __builtin_amdgcn_mfma_f32_16x16x32_bf16(afr[mi][0], b0, a, 0, 0, 0);
            a = __builtin_amdgcn_mfma_f32_16x16x32_bf16(afr[mi][1], b1, a, 0, 0, 0);
#pragma unroll
            for (int r = 0; r < 4; ++r) {
                int t = mi * 16 + fs * 4 + r;
                out[((size_t)(b * 4096) + t0 + t) * 1024 + col] = a[r] + bias;
            }
        }
    }
}

extern "C" void kernel_launch(void* const* d_in, const int* in_sizes, int n_in,
                              void* d_out, int out_size, void* d_ws, size_t ws_size,
                              hipStream_t stream) {
    const float* x          = (const float*)d_in[0];
    const float* conv_w     = (const float*)d_in[1];
    const float* conv_b     = (const float*)d_in[2];
    const float* in_proj_w  = (const float*)d_in[3];
    const float* in_proj_b  = (const float*)d_in[4];
    const float* A_log      = (const float*)d_in[5];
    const float* out_proj_w = (const float*)d_in[6];
    const float* out_proj_b = (const float*)d_in[7];
    float* out = (float*)d_out;

    char* w = (char*)d_ws;
    bf16*  Whg  = (bf16*)w;                                  // 393216 B
    bf16*  Wlg  = (bf16*)(w + 393216);                       // 393216 B
    bf16*  Wob  = (bf16*)(w + 786432);                       // 131072 B
    float* Abar = (float*)(w + 917504);                      // 8 MiB
    float* Bbar = (float*)(w + 917504 + 8388608);
    float* Cst  = (float*)(w + 917504 + 2 * 8388608);
    float* Psum = (float*)(w + 917504 + 3 * 8388608);        // 128 KiB each
    float* Ssum = (float*)(w + 917504 + 3 * 8388608 + 131072);
    float* Carry= (float*)(w + 917504 + 3 * 8388608 + 262144);

    hipLaunchKernelGGL(k0_prep,     dim3(1024), dim3(256), 0, stream,
                       in_proj_w, out_proj_w, Whg, Wlg, Wob);
    hipLaunchKernelGGL(k1_convproj, dim3(512),  dim3(256), 0, stream,
                       x, conv_w, conv_b, in_proj_b, A_log, Whg, Wlg,
                       Abar, Bbar, Cst, Psum, Ssum);
    hipLaunchKernelGGL(k2_scan2,    dim3(8),    dim3(64),  0, stream, Psum, Ssum, Carry);
    hipLaunchKernelGGL(k3_scan_out, dim3(512),  dim3(512), 0, stream,
                       Abar, Bbar, Cst, Carry, Wob, out_proj_b, out);
}

// Round 4
// 160.051 us; speedup vs baseline: 4.0344x; 1.3440x over previous
//
#include <hip/hip_runtime.h>
#include <cstdint>
#include <cstddef>

typedef __bf16 bf16;
typedef __attribute__((ext_vector_type(4))) __bf16 bf16x4;
typedef __attribute__((ext_vector_type(8))) __bf16 bf16x8;
typedef __attribute__((ext_vector_type(4))) float f32x4;

#define EPS_C 1e-4f
#define SWZ(r) (((r) ^ ((r) >> 2)) & 3)

// ================= K0: weights prep =================
// Whg/Wlg: reduced in_proj (192 x 1024) hi/lo bf16, CHUNK-MAJOR: [k/32][n][k%32]
// (each BK=32 tile contiguous 12 KB -> perfectly coalesced staging loads).
// Wob: out_proj_w bf16, [dm=1024][i=64] k-contig.
__global__ __launch_bounds__(256) void k0_prep(const float* __restrict__ Wi,
    const float* __restrict__ Wo, bf16* __restrict__ Whg, bf16* __restrict__ Wlg,
    bf16* __restrict__ Wob)
{
    int idx = blockIdx.x * 256 + threadIdx.x;
    if (idx < 192 * 1024) {
        int n = idx >> 10, k = idx & 1023;
        float w;
        if (n < 64) {
            w = Wi[n * 1024 + k];
        } else if (n < 128) {
            int i = n - 64;
            w = 0.5f * (Wi[(64 + 2 * i) * 1024 + k] + Wi[(65 + 2 * i) * 1024 + k]);
        } else {
            int i = n - 128;
            w = 0.5f * (Wi[(192 + 2 * i) * 1024 + k] + Wi[(193 + 2 * i) * 1024 + k]);
        }
        bf16 h = (bf16)w;
        int dst = (k >> 5) * 6144 + n * 32 + (k & 31);
        Whg[dst] = h;
        Wlg[dst] = (bf16)(w - (float)h);
    } else {
        int j = idx - 192 * 1024;
        if (j < 65536) Wob[j] = (bf16)Wo[j];
    }
}

// ================= K1: conv + split-bf16 MFMA in_proj + SSM + chunk-local scan =================
// 512 threads (8 waves), 2 blocks/CU (64 KB LDS), dbuf, 1 barrier/chunk.
// Block: 64t x 192n, BK=32. Wave: 32t x 48n -> acc[2][3], 18 MFMA/chunk.
__global__ __launch_bounds__(512, 4) void k1_convproj(
    const float* __restrict__ x, const float* __restrict__ conv_w,
    const float* __restrict__ conv_b, const float* __restrict__ in_proj_b,
    const float* __restrict__ A_log,
    const bf16* __restrict__ Whg, const bf16* __restrict__ Wlg,
    float* __restrict__ Yp, float* __restrict__ Zp,
    float* __restrict__ Psum, float* __restrict__ Ssum)
{
    __shared__ char smem[65536];
    // xh[2]@0/4096, xl[2]@8192/12288, wh[2]@16384/28672, wl[2]@40960/53248

    const int tid  = threadIdx.x;
    const int lane = tid & 63;
    const int wv   = tid >> 6;
    const int wt   = wv >> 2, wn = wv & 3;
    const int fr   = lane & 15, fs = lane >> 4;
    const int b    = blockIdx.x >> 6;
    const int tc   = blockIdx.x & 63;
    const int t0   = tc * 64;

    // conv/staging mapping: thread -> (t=ct, 4 channels at cs*4)
    const int ct = tid >> 3, cs = tid & 7;
    const int gt = t0 + ct;
    const bool zrow = (gt == 4095);                 // reference zero-pads last conv row
    const int xwo = ct * 64 + ((((cs >> 1) ^ SWZ(ct)) & 3) << 4) + (cs & 1) * 8;
    int wwo[3];
#pragma unroll
    for (int j = 0; j < 3; ++j) {
        int p = tid + 512 * j;
        int wr = p >> 3, k8 = p & 7;
        wwo[j] = wr * 64 + ((((k8 >> 1) ^ SWZ(wr)) & 3) << 4) + (k8 & 1) * 8;
    }
    int aoff[2], boff[3];
#pragma unroll
    for (int mi = 0; mi < 2; ++mi) { int r = wt * 32 + mi * 16 + fr; aoff[mi] = r * 64 + ((fs ^ SWZ(r)) << 4); }
#pragma unroll
    for (int ni = 0; ni < 3; ++ni) { int r = wn * 48 + ni * 16 + fr; boff[ni] = r * 64 + ((fs ^ SWZ(r)) << 4); }

    bool tapok[4];
#pragma unroll
    for (int dt = 0; dt < 4; ++dt) { int g = gt - 1 + dt; tapok[dt] = (g >= 0) && (g < 4096); }

    f32x4 xr[4];
    uint2 wrh[3], wrl[3];

    auto fetch = [&](int c) {                        // issue global loads for chunk c
        const int ch0 = c * 32 + cs * 4;
#pragma unroll
        for (int dt = 0; dt < 4; ++dt) {
            int g = gt - 1 + dt;
            size_t row = (size_t)(tapok[dt] ? g : 0);
            f32x4 v = *(const f32x4*)&x[((size_t)b * 4096 + row) * 1024 + ch0];
            f32x4 z = {0.f, 0.f, 0.f, 0.f};
            xr[dt] = tapok[dt] ? v : z;
        }
        const bf16* wbh = Whg + (size_t)c * 6144;
        const bf16* wbl = Wlg + (size_t)c * 6144;
#pragma unroll
        for (int j = 0; j < 3; ++j) {
            int p = (tid + 512 * j) * 4;
            wrh[j] = *(const uint2*)(wbh + p);
            wrl[j] = *(const uint2*)(wbl + p);
        }
    };

    auto stage = [&](int c, int pp) {                // conv chunk c, write LDS buffer pp
        char* xh = smem + pp * 4096;
        char* xl = smem + 8192 + pp * 4096;
        char* wh = smem + 16384 + pp * 12288;
        char* wl = smem + 40960 + pp * 12288;
        const int ch0 = c * 32 + cs * 4;
        bf16x4 hi, lo;
#pragma unroll
        for (int j = 0; j < 4; ++j) {
            float v = 0.f;
            if (!zrow) {
                f32x4 cw = *(const f32x4*)&conv_w[(ch0 + j) * 4];   // L1-hot table
                v = conv_b[ch0 + j];
                v = fmaf(cw.x, xr[0][j], v);
                v = fmaf(cw.y, xr[1][j], v);
                v = fmaf(cw.z, xr[2][j], v);
                v = fmaf(cw.w, xr[3][j], v);
            }
            bf16 h = (bf16)v;
            hi[j] = h;
            lo[j] = (bf16)(v - (float)h);
        }
        *(bf16x4*)(xh + xwo) = hi;
        *(bf16x4*)(xl + xwo) = lo;
#pragma unroll
        for (int j = 0; j < 3; ++j) {
            *(uint2*)(wh + wwo[j]) = wrh[j];
            *(uint2*)(wl + wwo[j]) = wrl[j];
        }
    };

    f32x4 acc[2][3] = {};

    fetch(0);
    stage(0, 0);
    __syncthreads();

#pragma unroll 1
    for (int c = 0; c < 32; ++c) {
        const int p = c & 1;
        if (c + 1 < 32) fetch(c + 1);                // loads in flight across MFMA phase
        const char* xh = smem + p * 4096;
        const char* xl = smem + 8192 + p * 4096;
        const char* wh = smem + 16384 + p * 12288;
        const char* wl = smem + 40960 + p * 12288;
        bf16x8 ah0 = *(const bf16x8*)(xh + aoff[0]);
        bf16x8 ah1 = *(const bf16x8*)(xh + aoff[1]);
        bf16x8 al0 = *(const bf16x8*)(xl + aoff[0]);
        bf16x8 al1 = *(const bf16x8*)(xl + aoff[1]);
#pragma unroll
        for (int ni = 0; ni < 3; ++ni) {
            bf16x8 bh = *(const bf16x8*)(wh + boff[ni]);
            bf16x8 bl = *(const bf16x8*)(wl + boff[ni]);
            acc[0][ni] = __builtin_amdgcn_mfma_f32_16x16x32_bf16(ah0, bh, acc[0][ni], 0, 0, 0);
            acc[1][ni] = __builtin_amdgcn_mfma_f32_16x16x32_bf16(ah1, bh, acc[1][ni], 0, 0, 0);
            acc[0][ni] = __builtin_amdgcn_mfma_f32_16x16x32_bf16(al0, bh, acc[0][ni], 0, 0, 0);
            acc[1][ni] = __builtin_amdgcn_mfma_f32_16x16x32_bf16(al1, bh, acc[1][ni], 0, 0, 0);
            acc[0][ni] = __builtin_amdgcn_mfma_f32_16x16x32_bf16(ah0, bl, acc[0][ni], 0, 0, 0);
            acc[1][ni] = __builtin_amdgcn_mfma_f32_16x16x32_bf16(ah1, bl, acc[1][ni], 0, 0, 0);
        }
        if (c + 1 < 32) stage(c + 1, p ^ 1);         // writes to other buffer
        __syncthreads();                             // one barrier per chunk
    }

    // ---- epilogue: transpose to res, SSM elementwise + full chunk-local scan ----
    float* res = (float*)smem;                       // [64 t][196]
#pragma unroll
    for (int mi = 0; mi < 2; ++mi)
#pragma unroll
        for (int ni = 0; ni < 3; ++ni) {
            int col = wn * 48 + ni * 16 + fr;
#pragma unroll
            for (int r = 0; r < 4; ++r) {
                int t = wt * 32 + mi * 16 + fs * 4 + r;
                res[t * 196 + col] = acc[mi][ni][r];
            }
        }
    __syncthreads();

    float* part = (float*)(smem + 50176);            // [2][8][64]
    const int i  = lane;
    const int tg = wv;
    const float A  = -expf(A_log[i]);
    const float bd = in_proj_b[i];
    const float bB = 0.5f * (in_proj_b[64 + 2 * i] + in_proj_b[65 + 2 * i]);
    const float bC = 0.5f * (in_proj_b[192 + 2 * i] + in_proj_b[193 + 2 * i]);
    const bool tiny = fabsf(A) < EPS_C;
    float av[8], bv[8], cv[8];
#pragma unroll
    for (int r = 0; r < 8; ++r) {
        int t = tg * 8 + r;
        float d  = res[t * 196 + i] + bd;
        float Bm = res[t * 196 + 64 + i] + bB;
        float Cm = res[t * 196 + 128 + i] + bC;
        float delta = (d > 20.f) ? d : log1pf(expf(d));
        float dA = delta * A;
        float abar = expf(dA);
        float sc = tiny ? (1.f + dA * 0.5f + dA * dA * (1.f / 6.f)) : ((abar - 1.f) / A);
        av[r] = abar; bv[r] = sc * Bm; cv[r] = Cm;
    }
    float P = 1.f, S = 0.f;
#pragma unroll
    for (int r = 0; r < 8; ++r) { S = fmaf(av[r], S, bv[r]); P *= av[r]; }
    part[tg * 64 + i] = P;
    part[512 + tg * 64 + i] = S;
    __syncthreads();
    float h = 0.f, pp = 1.f;
#pragma unroll
    for (int g = 0; g < 7; ++g)
        if (g < tg) {
            float Pg = part[g * 64 + i], Sg = part[512 + g * 64 + i];
            h = fmaf(Pg, h, Sg);
            pp *= Pg;
        }
    size_t ob = ((size_t)b * 4096 + t0 + tg * 8) * 64 + i;
#pragma unroll
    for (int r = 0; r < 8; ++r) {
        h  = fmaf(av[r], h, bv[r]);                  // chunk-local state
        pp *= av[r];                                 // chunk-local prefix product
        Yp[ob + (size_t)r * 64] = cv[r] * h;
        Zp[ob + (size_t)r * 64] = cv[r] * pp;
    }
    if (tg == 7) {
        size_t o = ((size_t)b * 64 + tc) * 64 + i;
        Psum[o] = pp;                                // full-chunk product
        Ssum[o] = h;                                 // full-chunk scan end
    }
}

// ================= K2: serial carry combine across 64 chunks =================
__global__ __launch_bounds__(64) void k2_scan2(const float* __restrict__ Psum,
    const float* __restrict__ Ssum, float* __restrict__ Carry)
{
    int b = blockIdx.x, i = threadIdx.x;
    float Pv[64], Sv[64];
#pragma unroll
    for (int c = 0; c < 64; ++c) {
        size_t o = ((size_t)(b * 64) + c) * 64 + i;
        Pv[c] = Psum[o]; Sv[c] = Ssum[o];
    }
    float h = 0.f;
#pragma unroll
    for (int c = 0; c < 64; ++c) {
        size_t o = ((size_t)(b * 64) + c) * 64 + i;
        Carry[o] = h;
        h = fmaf(Pv[c], h, Sv[c]);
    }
}

// ================= K3: y = Yp + Zp*carry, fused out_proj MFMA =================
__global__ __launch_bounds__(512) void k3_scan_out(
    const float* __restrict__ Yp, const float* __restrict__ Zp,
    const float* __restrict__ Carry, const bf16* __restrict__ Wob,
    const float* __restrict__ bo, float* __restrict__ out)
{
    __shared__ char sm3[8192];                       // [64 t][64 i] bf16, swizzled

    const int tid  = threadIdx.x;
    const int lane = tid & 63;
    const int wv   = tid >> 6;
    const int b    = blockIdx.x >> 6;
    const int ch   = blockIdx.x & 63;
    const int t0   = ch * 64;

    const int i = lane, tg = wv;
    float cr = Carry[((size_t)(b * 64) + ch) * 64 + i];
    size_t base = ((size_t)(b * 4096) + t0 + tg * 8) * 64 + i;
#pragma unroll
    for (int r = 0; r < 8; ++r) {
        float y = Yp[base + (size_t)r * 64] + Zp[base + (size_t)r * 64] * cr;
        int t = tg * 8 + r;
        int off = t * 128 + ((((i >> 3) ^ (t & 7)) & 7) << 4) + (i & 7) * 2;
        *(bf16*)(sm3 + off) = (bf16)y;
    }
    __syncthreads();

    const int fr = lane & 15, fs = lane >> 4;
    bf16x8 afr[4][2];
#pragma unroll
    for (int mi = 0; mi < 4; ++mi)
#pragma unroll
        for (int ks = 0; ks < 2; ++ks) {
            int row = mi * 16 + fr;
            int slot = ks * 4 + fs;
            int off = row * 128 + (((slot ^ (row & 7)) & 7) << 4);
            afr[mi][ks] = *(const bf16x8*)(sm3 + off);
        }
    const int n0 = wv * 128;
#pragma unroll
    for (int ni = 0; ni < 8; ++ni) {
        int col = n0 + ni * 16 + fr;
        bf16x8 b0 = *(const bf16x8*)(Wob + (size_t)col * 64 + fs * 8);
        bf16x8 b1 = *(const bf16x8*)(Wob + (size_t)col * 64 + 32 + fs * 8);
        float bias = bo[col];
#pragma unroll
        for (int mi = 0; mi < 4; ++mi) {
            f32x4 a = {};
            a = __builtin_amdgcn_mfma_f32_16x16x32_bf16(afr[mi][0], b0, a, 0, 0, 0);
            a = __builtin_amdgcn_mfma_f32_16x16x32_bf16(afr[mi][1], b1, a, 0, 0, 0);
#pragma unroll
            for (int r = 0; r < 4; ++r) {
                int t = mi * 16 + fs * 4 + r;
                out[((size_t)(b * 4096) + t0 + t) * 1024 + col] = a[r] + bias;
            }
        }
    }
}

extern "C" void kernel_launch(void* const* d_in, const int* in_sizes, int n_in,
                              void* d_out, int out_size, void* d_ws, size_t ws_size,
                              hipStream_t stream) {
    const float* x          = (const float*)d_in[0];
    const float* conv_w     = (const float*)d_in[1];
    const float* conv_b     = (const float*)d_in[2];
    const float* in_proj_w  = (const float*)d_in[3];
    const float* in_proj_b  = (const float*)d_in[4];
    const float* A_log      = (const float*)d_in[5];
    const float* out_proj_w = (const float*)d_in[6];
    const float* out_proj_b = (const float*)d_in[7];
    float* out = (float*)d_out;

    char* w = (char*)d_ws;
    bf16*  Whg  = (bf16*)w;                                   // 393216 B
    bf16*  Wlg  = (bf16*)(w + 393216);                        // 393216 B
    bf16*  Wob  = (bf16*)(w + 786432);                        // 131072 B
    float* Yp   = (float*)(w + 917504);                       // 8 MiB
    float* Zp   = (float*)(w + 917504 + 8388608);             // 8 MiB
    float* Psum = (float*)(w + 917504 + 2 * 8388608);         // 128 KiB
    float* Ssum = (float*)(w + 917504 + 2 * 8388608 + 131072);
    float* Carry= (float*)(w + 917504 + 2 * 8388608 + 262144);

    hipLaunchKernelGGL(k0_prep,     dim3(1024), dim3(256), 0, stream,
                       in_proj_w, out_proj_w, Whg, Wlg, Wob);
    hipLaunchKernelGGL(k1_convproj, dim3(512),  dim3(512), 0, stream,
                       x, conv_w, conv_b, in_proj_b, A_log, Whg, Wlg,
                       Yp, Zp, Psum, Ssum);
    hipLaunchKernelGGL(k2_scan2,    dim3(8),    dim3(64),  0, stream, Psum, Ssum, Carry);
    hipLaunchKernelGGL(k3_scan_out, dim3(512),  dim3(512), 0, stream,
                       Yp, Zp, Carry, Wob, out_proj_b, out);
}